// Round 29
// baseline (42.076 us; speedup 1.0000x reference)
//
#include <hip/hip_runtime.h>
#include <hip/hip_bf16.h>

// Self-attention, fused QKV: x[4,2048,1024] f32, Wq/Wk/Wv[1024,64] f32 -> out[4,2048,64] f32
// bf16 MFMA (16x16x32), fp32 accumulation.
//   K1: wtrans  -- W -> Wt bf16 [192][1024], LDS tile-transpose.
//   K2: qkv_proj -- counted-vmcnt pipeline with DECOUPLED A/B issue: A (cold HBM x)
//       issued 3 gens ahead (2-step lead, areg 3-parity), B (L2-hot Wt gload_lds)
//       2 gens ahead. LDS stays 3x16KB -> 3 blocks/CU (r27's depth-3 LDS cost avoided).
//   K3: attn32  -- r26 proven: 32-query tiles, K parity-prefetch + early-V regs.

typedef __attribute__((ext_vector_type(8))) short bf16x8;
typedef __attribute__((ext_vector_type(4))) float f32x4;
typedef __attribute__((ext_vector_type(4))) unsigned short u16x4;

#define QSCALE 0.1803368801111832f   // 0.125 * log2(e); logits land in exp2 domain

__device__ __forceinline__ short f2bf(float f) {
    union { float f; unsigned u; } v; v.f = f;
    unsigned r = v.u + 0x7FFF + ((v.u >> 16) & 1);   // round-to-nearest-even
    return (short)(r >> 16);
}

// packed f32 pair -> 2x bf16 in one v_cvt_pk_bf16_f32
__device__ __forceinline__ unsigned pk2(float a, float b) {
    union { __hip_bfloat162 h; unsigned u; } v;
    v.h = __float22bfloat162_rn(make_float2(a, b));
    return v.u;
}

__device__ __forceinline__ void gload16(const void* src, void* dst) {
    __builtin_amdgcn_global_load_lds(
        (const __attribute__((address_space(1))) unsigned int*)src,
        (__attribute__((address_space(3))) unsigned int*)dst, 16, 0, 0);
}

// ---------------- K1: weight transpose + bf16 convert (coalesced) ----------------
__global__ __launch_bounds__(256) void wtrans(const float* __restrict__ Wq,
                                              const float* __restrict__ Wk,
                                              const float* __restrict__ Wv,
                                              short* __restrict__ Wt) {
    __shared__ short lds[64][66];
    int warr = blockIdx.x / 16;
    int d0 = (blockIdx.x % 16) * 64;
    const float* W = (warr == 0) ? Wq : (warr == 1) ? Wk : Wv;
    int rg = threadIdx.x >> 6;
    int c  = threadIdx.x & 63;
    #pragma unroll
    for (int p = 0; p < 16; ++p) {
        int d = p * 4 + rg;
        lds[d][c] = f2bf(W[(d0 + d) * 64 + c]);
    }
    __syncthreads();
    #pragma unroll
    for (int p = 0; p < 16; ++p) {
        int n = p * 4 + rg;
        Wt[(warr * 64 + n) * 1024 + d0 + c] = lds[c][n];
    }
}

// ---------------- K2: QKV projection, decoupled A/B counted-vmcnt pipeline ----------------
// grid = 512 blocks (256 M-tiles x 2 N-halves), 256 thr (4 waves). Tile M=32 x N=96, BK=64.
// Buffer (16KB): A bf16 [32 rows][64 shorts] XOR-swizzled @0; B bf16 12x1KB chunks @4096.
// A-loads (HBM-cold x): issued at t+3, consumed by WRITEA at t+1 -> 2-step lead.
// B-gloads (L2-hot Wt): issued at t+2, consumed at t+1-compute -> 1-step lead.
// End-of-step wait confirms B(t+1): newer = A(t+3)x2 + B(t+2)x3 -> vmcnt(5).
__global__ __launch_bounds__(256, 3) void qkv_proj(const float* __restrict__ x,
                                                   const short* __restrict__ Wt,
                                                   short* __restrict__ Q,
                                                   short* __restrict__ K,
                                                   short* __restrict__ Vt) {
    __shared__ char stage_lds[3][16384];

    int tid = threadIdx.x;
    int wid = tid >> 6, lane = tid & 63;
    int l15 = lane & 15, lg = lane >> 4;
    int wr = wid >> 1, wn = wid & 1;
    int logical = (blockIdx.x & 7) * 64 + (blockIdx.x >> 3);
    int mbase = (logical >> 1) * 32;
    int nbase = (logical & 1) * 96;

    int arow_s = tid >> 3, aslot = tid & 7;
    const float* a_src = x + (mbase + arow_s) * 1024 + aslot * 8;
    int a_woff = arow_s * 128 + ((aslot ^ (arow_s & 7)) << 4);

    int b_soff[3];
    #pragma unroll
    for (int j = 0; j < 3; ++j) {
        int cb = wid + j * 4;
        int row = cb * 8 + (lane >> 3);
        int ss = (lane & 7) ^ (row & 7);
        b_soff[j] = (nbase + row) * 1024 + ss * 8;
    }

    f32x4 acc[3];
    #pragma unroll
    for (int f = 0; f < 3; ++f) acc[f] = (f32x4){0.f, 0.f, 0.f, 0.f};

    float4 areg[3][2];   // 3 generations of A rows in flight (2-step lead)

#define ISSUE_A(g)                                                            \
    {                                                                         \
        const float* ap_ = a_src + (g) * 64;                                  \
        areg[(g) % 3][0] = *(const float4*)ap_;                               \
        areg[(g) % 3][1] = *(const float4*)(ap_ + 4);                         \
    }

#define ISSUE_B(g)                                                            \
    {                                                                         \
        char* bb_ = &stage_lds[(g) % 3][4096];                                \
        _Pragma("unroll")                                                     \
        for (int j = 0; j < 3; ++j)                                           \
            gload16(Wt + b_soff[j] + (g) * 64, bb_ + (wid + j * 4) * 1024);   \
    }

#define WRITEA(g)                                                             \
    {                                                                         \
        float4 f0_ = areg[(g) % 3][0], f1_ = areg[(g) % 3][1];                \
        union { bf16x8 v; unsigned u[4]; } au_;                               \
        au_.u[0] = pk2(f0_.x, f0_.y); au_.u[1] = pk2(f0_.z, f0_.w);           \
        au_.u[2] = pk2(f1_.x, f1_.y); au_.u[3] = pk2(f1_.z, f1_.w);           \
        *(bf16x8*)(&stage_lds[(g) % 3][0] + a_woff) = au_.v;                  \
    }

    // prologue: A gets 2-gen lead; confirming B(0) leaves A(2)+B(1) in flight
    ISSUE_A(0);
    ISSUE_A(1);
    ISSUE_B(0);
    ISSUE_A(2);
    ISSUE_B(1);
    WRITEA(0);
    asm volatile("s_waitcnt vmcnt(5) lgkmcnt(0)" ::: "memory");
    __builtin_amdgcn_s_barrier();
    __builtin_amdgcn_sched_barrier(0);

    #pragma unroll
    for (int t = 0; t < 16; ++t) {
        if (t + 3 < 16) ISSUE_A(t + 3);
        if (t + 2 < 16) ISSUE_B(t + 2);
        if (t + 1 < 16) WRITEA(t + 1);    // A issued 2 steps ago: latency covered
        const char* Ab = &stage_lds[t % 3][0];
        const char* Bb = &stage_lds[t % 3][4096];
        int arow = wr * 16 + l15;
        __builtin_amdgcn_s_setprio(1);
        #pragma unroll
        for (int h = 0; h < 2; ++h) {
            int sA = (h * 4 + lg) ^ (arow & 7);
            bf16x8 a = *(const bf16x8*)(Ab + arow * 128 + sA * 16);
            #pragma unroll
            for (int f = 0; f < 3; ++f) {
                int brow = (wn * 3 + f) * 16 + l15;
                int ss = (h * 4 + lg) ^ (brow & 7);
                bf16x8 b = *(const bf16x8*)(Bb + brow * 128 + ss * 16);
                acc[f] = __builtin_amdgcn_mfma_f32_16x16x32_bf16(a, b, acc[f], 0, 0, 0);
            }
        }
        __builtin_amdgcn_s_setprio(0);
        if (t < 15) {
            if (t + 3 < 16) {
                asm volatile("s_waitcnt vmcnt(5) lgkmcnt(0)" ::: "memory");
            } else if (t + 2 < 16) {
                asm volatile("s_waitcnt vmcnt(3) lgkmcnt(0)" ::: "memory");
            } else {
                asm volatile("s_waitcnt vmcnt(0) lgkmcnt(0)" ::: "memory");
            }
            __builtin_amdgcn_s_barrier();
            __builtin_amdgcn_sched_barrier(0);
        }
    }
#undef ISSUE_A
#undef ISSUE_B
#undef WRITEA

    __syncthreads();
    short* Vl = (short*)&stage_lds[0][0];   // [32][72]
    #pragma unroll
    for (int f = 0; f < 3; ++f) {
        int n = nbase + (wn * 3 + f) * 16 + l15;
        #pragma unroll
        for (int r = 0; r < 4; ++r) {
            int ml = wr * 16 + lg * 4 + r;
            int m = mbase + ml;
            float v = acc[f][r];
            if (n < 64) {
                Q[m * 64 + n] = f2bf(v * QSCALE);
            } else if (n < 128) {
                K[m * 64 + (n - 64)] = f2bf(v);
            } else {
                Vl[ml * 72 + (n - 128)] = f2bf(v);
            }
        }
    }
    if (nbase == 96) {
        __syncthreads();
        int dk = tid >> 2;
        int m0 = (tid & 3) * 8;
        int b_ = mbase >> 11;
        int s_ = mbase & 2047;
        #pragma unroll
        for (int j = 0; j < 2; ++j) {
            u16x4 v;
            #pragma unroll
            for (int i = 0; i < 4; ++i) v[i] = (unsigned short)Vl[(m0 + j * 4 + i) * 72 + dk];
            *(u16x4*)&Vt[(b_ * 64 + dk) * 2048 + s_ + m0 + j * 4] = v;
        }
    }
}

// ---------------- K3: flash attention, 32-query tiles, reg-pipelined K/V (r26) ----------------
__global__ __launch_bounds__(512, 2) void attn32(const short* __restrict__ Q,
                                                 const short* __restrict__ K,
                                                 const short* __restrict__ Vt,
                                                 float* __restrict__ out) {
    __shared__ char ubuf[8][8704];   // per-wave: P [32][72]s | accw [32][68]f (union)
    __shared__ float Mw[8][32];
    __shared__ float Lw[8][32];
    __shared__ float Ltot[32];

    int tid = threadIdx.x, wid = tid >> 6, lane = tid & 63;
    int l15 = lane & 15, lg = lane >> 4;
    int logical = (blockIdx.x & 7) * 32 + (blockIdx.x >> 3);
    int b_ = logical >> 6;
    int q0 = (logical & 63) * 32;
    const short* Kb = K + b_ * 2048 * 64;
    const short* Vb = Vt + b_ * 64 * 2048;

    bf16x8 bq[2][2];
    #pragma unroll
    for (int qg = 0; qg < 2; ++qg) {
        const short* Qp = Q + (b_ * 2048 + q0 + qg * 16 + l15) * 64 + lg * 8;
        bq[qg][0] = *(const bf16x8*)Qp;
        bq[qg][1] = *(const bf16x8*)(Qp + 32);
    }

    short* P = (short*)&ubuf[wid][0];          // [32][72]

    f32x4 acc[2][4];
    #pragma unroll
    for (int qg = 0; qg < 2; ++qg)
        #pragma unroll
        for (int t = 0; t < 4; ++t) acc[qg][t] = (f32x4){0.f, 0.f, 0.f, 0.f};
    float m_run[2] = {-INFINITY, -INFINITY};
    float l_run[2] = {0.f, 0.f};

    int kv0 = wid * 256;

    bf16x8 kr[2][8];
    #pragma unroll
    for (int kt = 0; kt < 4; ++kt) {
        const short* Kp = Kb + (kv0 + kt * 16 + l15) * 64 + lg * 8;
        kr[0][kt * 2]     = *(const bf16x8*)Kp;
        kr[0][kt * 2 + 1] = *(const bf16x8*)(Kp + 32);
    }

    #pragma unroll
    for (int t = 0; t < 4; ++t) {
        int kv = kv0 + t * 64;

        bf16x8 vr[8];
        #pragma unroll
        for (int ps = 0; ps < 2; ++ps)
            #pragma unroll
            for (int tt = 0; tt < 4; ++tt)
                vr[ps * 4 + tt] = *(const bf16x8*)(Vb + (tt * 16 + l15) * 2048 + kv + ps * 32 + lg * 8);

        f32x4 s[2][4];
        __builtin_amdgcn_s_setprio(1);
        #pragma unroll
        for (int kt = 0; kt < 4; ++kt) {
            f32x4 z0 = (f32x4){0.f, 0.f, 0.f, 0.f};
            z0 = __builtin_amdgcn_mfma_f32_16x16x32_bf16(kr[t & 1][kt * 2], bq[0][0], z0, 0, 0, 0);
            s[0][kt] = __builtin_amdgcn_mfma_f32_16x16x32_bf16(kr[t & 1][kt * 2 + 1], bq[0][1], z0, 0, 0, 0);
            f32x4 z1 = (f32x4){0.f, 0.f, 0.f, 0.f};
            z1 = __builtin_amdgcn_mfma_f32_16x16x32_bf16(kr[t & 1][kt * 2], bq[1][0], z1, 0, 0, 0);
            s[1][kt] = __builtin_amdgcn_mfma_f32_16x16x32_bf16(kr[t & 1][kt * 2 + 1], bq[1][1], z1, 0, 0, 0);
        }
        __builtin_amdgcn_s_setprio(0);

        if (t < 3) {
            #pragma unroll
            for (int kt = 0; kt < 4; ++kt) {
                const short* Kp = Kb + (kv + 64 + kt * 16 + l15) * 64 + lg * 8;
                kr[(t + 1) & 1][kt * 2]     = *(const bf16x8*)Kp;
                kr[(t + 1) & 1][kt * 2 + 1] = *(const bf16x8*)(Kp + 32);
            }
        }

        #pragma unroll
        for (int qg = 0; qg < 2; ++qg) {
            float m01 = fmaxf(fmaxf(s[qg][0][0], s[qg][0][1]), fmaxf(s[qg][0][2], s[qg][0][3]));
            float m23 = fmaxf(fmaxf(s[qg][1][0], s[qg][1][1]), fmaxf(s[qg][1][2], s[qg][1][3]));
            float m45 = fmaxf(fmaxf(s[qg][2][0], s[qg][2][1]), fmaxf(s[qg][2][2], s[qg][2][3]));
            float m67 = fmaxf(fmaxf(s[qg][3][0], s[qg][3][1]), fmaxf(s[qg][3][2], s[qg][3][3]));
            float mt = fmaxf(fmaxf(m01, m23), fmaxf(m45, m67));
            mt = fmaxf(mt, __shfl_xor(mt, 16));
            mt = fmaxf(mt, __shfl_xor(mt, 32));
            if (!__all(mt - m_run[qg] <= 8.0f)) {
                float mn = fmaxf(m_run[qg], mt);
                float c = exp2f(m_run[qg] - mn);
                m_run[qg] = mn;
                l_run[qg] *= c;
                #pragma unroll
                for (int tt = 0; tt < 4; ++tt)
                    #pragma unroll
                    for (int r = 0; r < 4; ++r) acc[qg][tt][r] *= c;
            }
            float rs = 0.f;
            #pragma unroll
            for (int kt = 0; kt < 4; ++kt)
                #pragma unroll
                for (int r = 0; r < 4; ++r) {
                    float p = exp2f(s[qg][kt][r] - m_run[qg]);
                    s[qg][kt][r] = p;
                    rs += p;
                }
            rs += __shfl_xor(rs, 16);
            rs += __shfl_xor(rs, 32);
            l_run[qg] += rs;
        }

        #pragma unroll
        for (int qg = 0; qg < 2; ++qg)
            #pragma unroll
            for (int kt = 0; kt < 4; ++kt) {
                union { u16x4 v; unsigned u[2]; } h;
                h.u[0] = pk2(s[qg][kt][0], s[qg][kt][1]);
                h.u[1] = pk2(s[qg][kt][2], s[qg][kt][3]);
                *(u16x4*)&P[(qg * 16 + l15) * 72 + kt * 16 + lg * 4] = h.v;
            }

        __builtin_amdgcn_s_setprio(1);
        #pragma unroll
        for (int ps = 0; ps < 2; ++ps) {
            bf16x8 bp0 = *(const bf16x8*)&P[l15 * 72 + ps * 32 + lg * 8];
            bf16x8 bp1 = *(const bf16x8*)&P[(16 + l15) * 72 + ps * 32 + lg * 8];
            #pragma unroll
            for (int tt = 0; tt < 4; ++tt) {
                acc[0][tt] = __builtin_amdgcn_mfma_f32_16x16x32_bf16(vr[ps * 4 + tt], bp0, acc[0][tt], 0, 0, 0);
                acc[1][tt] = __builtin_amdgcn_mfma_f32_16x16x32_bf16(vr[ps * 4 + tt], bp1, acc[1][tt], 0, 0, 0);
            }
        }
        __builtin_amdgcn_s_setprio(0);
    }

    if (lg == 0) {
        #pragma unroll
        for (int qg = 0; qg < 2; ++qg) {
            Mw[wid][qg * 16 + l15] = m_run[qg];
            Lw[wid][qg * 16 + l15] = l_run[qg];
        }
    }
    __syncthreads();   // all PV reads of P done; ubuf reusable as accw

    float* accw = (float*)&ubuf[wid][0];       // [32][68]
    #pragma unroll
    for (int qg = 0; qg < 2; ++qg) {
        int row = qg * 16 + l15;
        float m = Mw[0][row];
        #pragma unroll
        for (int w = 1; w < 8; ++w) m = fmaxf(m, Mw[w][row]);
        float fac = exp2f(m_run[qg] - m);
        #pragma unroll
        for (int t = 0; t < 4; ++t) {
            f32x4 v = acc[qg][t];
            v[0] *= fac; v[1] *= fac; v[2] *= fac; v[3] *= fac;
            *(f32x4*)&accw[row * 68 + t * 16 + lg * 4] = v;
        }
    }

    if (wid == 0 && lg == 0) {
        #pragma unroll
        for (int qg = 0; qg < 2; ++qg) {
            int row = qg * 16 + l15;
            float m = Mw[0][row];
            #pragma unroll
            for (int w = 1; w < 8; ++w) m = fmaxf(m, Mw[w][row]);
            float L = 0.f;
            #pragma unroll
            for (int w = 0; w < 8; ++w)
                L += Lw[w][row] * exp2f(Mw[w][row] - m);
            Ltot[row] = L;
        }
    }
    __syncthreads();

    #pragma unroll
    for (int j = 0; j < 4; ++j) {
        int o = tid + j * 512;
        int row = o >> 6, col = o & 63;
        float ssum = 0.f;
        #pragma unroll
        for (int w = 0; w < 8; ++w)
            ssum += ((const float*)&ubuf[w][0])[row * 68 + col];
        out[(b_ * 2048 + q0 + row) * 64 + col] = ssum / Ltot[row];
    }
}

extern "C" void kernel_launch(void* const* d_in, const int* in_sizes, int n_in,
                              void* d_out, int out_size, void* d_ws, size_t ws_size,
                              hipStream_t stream) {
    const float* x  = (const float*)d_in[0];
    const float* Wq = (const float*)d_in[1];
    const float* Wk = (const float*)d_in[2];
    const float* Wv = (const float*)d_in[3];
    float* out = (float*)d_out;

    char* ws = (char*)d_ws;
    short* Wt = (short*)ws;                              // 393216 B
    short* Q  = (short*)(ws + 393216);                   // 1048576 B
    short* K  = (short*)(ws + 393216 + 1048576);         // 1048576 B
    short* Vt = (short*)(ws + 393216 + 2 * 1048576);     // 1048576 B  (~3.4 MB total)

    hipLaunchKernelGGL(wtrans,   dim3(48),  dim3(256), 0, stream, Wq, Wk, Wv, Wt);
    hipLaunchKernelGGL(qkv_proj, dim3(512), dim3(256), 0, stream, x, Wt, Q, K, Vt);
    hipLaunchKernelGGL(attn32,   dim3(256), dim3(512), 0, stream, Q, K, Vt, out);
}

// Round 30
// 41.780 us; speedup vs baseline: 1.0071x; 1.0071x over previous
//
#include <hip/hip_runtime.h>
#include <hip/hip_bf16.h>

// Self-attention, fused QKV: x[4,2048,1024] f32, Wq/Wk/Wv[1024,64] f32 -> out[4,2048,64] f32
// bf16 MFMA (16x16x32), fp32 accumulation.  [FINAL: r28 best-measured build, 41.78 us]
//   K1: wtrans  -- W -> Wt bf16 [192][1024], LDS tile-transpose.
//   K2: qkv_proj -- bf16-A-staged counted-vmcnt pipeline, depth 2 (3x16KB buffers,
//       vmcnt(5)), 3 blocks/CU. (depth-3 and A/B-decoupled variants measured slower)
//   K3: attn32  -- 32-query tiles, K parity-prefetch + early-V regs, T13 defer-max.

typedef __attribute__((ext_vector_type(8))) short bf16x8;
typedef __attribute__((ext_vector_type(4))) float f32x4;
typedef __attribute__((ext_vector_type(4))) unsigned short u16x4;

#define QSCALE 0.1803368801111832f   // 0.125 * log2(e); logits land in exp2 domain

__device__ __forceinline__ short f2bf(float f) {
    union { float f; unsigned u; } v; v.f = f;
    unsigned r = v.u + 0x7FFF + ((v.u >> 16) & 1);   // round-to-nearest-even
    return (short)(r >> 16);
}

// packed f32 pair -> 2x bf16 in one v_cvt_pk_bf16_f32
__device__ __forceinline__ unsigned pk2(float a, float b) {
    union { __hip_bfloat162 h; unsigned u; } v;
    v.h = __float22bfloat162_rn(make_float2(a, b));
    return v.u;
}

__device__ __forceinline__ void gload16(const void* src, void* dst) {
    __builtin_amdgcn_global_load_lds(
        (const __attribute__((address_space(1))) unsigned int*)src,
        (__attribute__((address_space(3))) unsigned int*)dst, 16, 0, 0);
}

// ---------------- K1: weight transpose + bf16 convert (coalesced) ----------------
__global__ __launch_bounds__(256) void wtrans(const float* __restrict__ Wq,
                                              const float* __restrict__ Wk,
                                              const float* __restrict__ Wv,
                                              short* __restrict__ Wt) {
    __shared__ short lds[64][66];
    int warr = blockIdx.x / 16;
    int d0 = (blockIdx.x % 16) * 64;
    const float* W = (warr == 0) ? Wq : (warr == 1) ? Wk : Wv;
    int rg = threadIdx.x >> 6;
    int c  = threadIdx.x & 63;
    #pragma unroll
    for (int p = 0; p < 16; ++p) {
        int d = p * 4 + rg;
        lds[d][c] = f2bf(W[(d0 + d) * 64 + c]);
    }
    __syncthreads();
    #pragma unroll
    for (int p = 0; p < 16; ++p) {
        int n = p * 4 + rg;
        Wt[(warr * 64 + n) * 1024 + d0 + c] = lds[c][n];
    }
}

// ---------------- K2: QKV projection, bf16-A-staged counted-vmcnt pipeline ----------------
// grid = 512 blocks (256 M-tiles x 2 N-halves), 256 thr (4 waves). Tile M=32 x N=96, BK=64.
// Buffer (16KB): A bf16 [32 rows][64 shorts] XOR-swizzled @0; B bf16 12x1KB chunks @4096.
// A: reg-staged (2x float4 load -> 4x pk2 -> ds_write_b128 swizzled). B: gload_lds,
// linear dest + pre-swizzled source. 3 buffers = 48KB -> 3 blocks/CU.
__global__ __launch_bounds__(256, 3) void qkv_proj(const float* __restrict__ x,
                                                   const short* __restrict__ Wt,
                                                   short* __restrict__ Q,
                                                   short* __restrict__ K,
                                                   short* __restrict__ Vt) {
    __shared__ char stage_lds[3][16384];

    int tid = threadIdx.x;
    int wid = tid >> 6, lane = tid & 63;
    int l15 = lane & 15, lg = lane >> 4;
    int wr = wid >> 1, wn = wid & 1;
    int logical = (blockIdx.x & 7) * 64 + (blockIdx.x >> 3);
    int mbase = (logical >> 1) * 32;
    int nbase = (logical & 1) * 96;

    int arow_s = tid >> 3, aslot = tid & 7;
    const float* a_src = x + (mbase + arow_s) * 1024 + aslot * 8;
    int a_woff = arow_s * 128 + ((aslot ^ (arow_s & 7)) << 4);

    int b_soff[3];
    #pragma unroll
    for (int j = 0; j < 3; ++j) {
        int cb = wid + j * 4;
        int row = cb * 8 + (lane >> 3);
        int ss = (lane & 7) ^ (row & 7);
        b_soff[j] = (nbase + row) * 1024 + ss * 8;
    }

    f32x4 acc[3];
    #pragma unroll
    for (int f = 0; f < 3; ++f) acc[f] = (f32x4){0.f, 0.f, 0.f, 0.f};

    float4 areg[2][2];

#define ISSUE(g)                                                              \
    {                                                                         \
        const float* ap_ = a_src + (g) * 64;                                  \
        areg[(g) & 1][0] = *(const float4*)ap_;                               \
        areg[(g) & 1][1] = *(const float4*)(ap_ + 4);                         \
        char* bb_ = &stage_lds[(g) % 3][4096];                                \
        _Pragma("unroll")                                                     \
        for (int j = 0; j < 3; ++j)                                           \
            gload16(Wt + b_soff[j] + (g) * 64, bb_ + (wid + j * 4) * 1024);   \
    }

#define WRITEA(g)                                                             \
    {                                                                         \
        float4 f0_ = areg[(g) & 1][0], f1_ = areg[(g) & 1][1];                \
        union { bf16x8 v; unsigned u[4]; } au_;                               \
        au_.u[0] = pk2(f0_.x, f0_.y); au_.u[1] = pk2(f0_.z, f0_.w);           \
        au_.u[2] = pk2(f1_.x, f1_.y); au_.u[3] = pk2(f1_.z, f1_.w);           \
        *(bf16x8*)(&stage_lds[(g) % 3][0] + a_woff) = au_.v;                  \
    }

    ISSUE(0);
    ISSUE(1);
    WRITEA(0);
    asm volatile("s_waitcnt vmcnt(5) lgkmcnt(0)" ::: "memory");
    __builtin_amdgcn_s_barrier();
    __builtin_amdgcn_sched_barrier(0);

    #pragma unroll
    for (int t = 0; t < 16; ++t) {
        if (t + 2 < 16) ISSUE(t + 2);
        if (t + 1 < 16) WRITEA(t + 1);
        const char* Ab = &stage_lds[t % 3][0];
        const char* Bb = &stage_lds[t % 3][4096];
        int arow = wr * 16 + l15;
        __builtin_amdgcn_s_setprio(1);
        #pragma unroll
        for (int h = 0; h < 2; ++h) {
            int sA = (h * 4 + lg) ^ (arow & 7);
            bf16x8 a = *(const bf16x8*)(Ab + arow * 128 + sA * 16);
            #pragma unroll
            for (int f = 0; f < 3; ++f) {
                int brow = (wn * 3 + f) * 16 + l15;
                int ss = (h * 4 + lg) ^ (brow & 7);
                bf16x8 b = *(const bf16x8*)(Bb + brow * 128 + ss * 16);
                acc[f] = __builtin_amdgcn_mfma_f32_16x16x32_bf16(a, b, acc[f], 0, 0, 0);
            }
        }
        __builtin_amdgcn_s_setprio(0);
        if (t < 15) {
            if (t + 2 < 16) {
                asm volatile("s_waitcnt vmcnt(5) lgkmcnt(0)" ::: "memory");
            } else {
                asm volatile("s_waitcnt vmcnt(0) lgkmcnt(0)" ::: "memory");
            }
            __builtin_amdgcn_s_barrier();
            __builtin_amdgcn_sched_barrier(0);
        }
    }
#undef ISSUE
#undef WRITEA

    __syncthreads();
    short* Vl = (short*)&stage_lds[0][0];   // [32][72]
    #pragma unroll
    for (int f = 0; f < 3; ++f) {
        int n = nbase + (wn * 3 + f) * 16 + l15;
        #pragma unroll
        for (int r = 0; r < 4; ++r) {
            int ml = wr * 16 + lg * 4 + r;
            int m = mbase + ml;
            float v = acc[f][r];
            if (n < 64) {
                Q[m * 64 + n] = f2bf(v * QSCALE);
            } else if (n < 128) {
                K[m * 64 + (n - 64)] = f2bf(v);
            } else {
                Vl[ml * 72 + (n - 128)] = f2bf(v);
            }
        }
    }
    if (nbase == 96) {
        __syncthreads();
        int dk = tid >> 2;
        int m0 = (tid & 3) * 8;
        int b_ = mbase >> 11;
        int s_ = mbase & 2047;
        #pragma unroll
        for (int j = 0; j < 2; ++j) {
            u16x4 v;
            #pragma unroll
            for (int i = 0; i < 4; ++i) v[i] = (unsigned short)Vl[(m0 + j * 4 + i) * 72 + dk];
            *(u16x4*)&Vt[(b_ * 64 + dk) * 2048 + s_ + m0 + j * 4] = v;
        }
    }
}

// ---------------- K3: flash attention, 32-query tiles, reg-pipelined K/V ----------------
// grid = 4*64 = 256 blocks, 512 thr (8 waves). Wave: 32 queries x 256-key slice.
__global__ __launch_bounds__(512, 2) void attn32(const short* __restrict__ Q,
                                                 const short* __restrict__ K,
                                                 const short* __restrict__ Vt,
                                                 float* __restrict__ out) {
    __shared__ char ubuf[8][8704];   // per-wave: P [32][72]s | accw [32][68]f (union)
    __shared__ float Mw[8][32];
    __shared__ float Lw[8][32];
    __shared__ float Ltot[32];

    int tid = threadIdx.x, wid = tid >> 6, lane = tid & 63;
    int l15 = lane & 15, lg = lane >> 4;
    int logical = (blockIdx.x & 7) * 32 + (blockIdx.x >> 3);
    int b_ = logical >> 6;
    int q0 = (logical & 63) * 32;
    const short* Kb = K + b_ * 2048 * 64;
    const short* Vb = Vt + b_ * 64 * 2048;

    bf16x8 bq[2][2];
    #pragma unroll
    for (int qg = 0; qg < 2; ++qg) {
        const short* Qp = Q + (b_ * 2048 + q0 + qg * 16 + l15) * 64 + lg * 8;
        bq[qg][0] = *(const bf16x8*)Qp;
        bq[qg][1] = *(const bf16x8*)(Qp + 32);
    }

    short* P = (short*)&ubuf[wid][0];          // [32][72]

    f32x4 acc[2][4];
    #pragma unroll
    for (int qg = 0; qg < 2; ++qg)
        #pragma unroll
        for (int t = 0; t < 4; ++t) acc[qg][t] = (f32x4){0.f, 0.f, 0.f, 0.f};
    float m_run[2] = {-INFINITY, -INFINITY};
    float l_run[2] = {0.f, 0.f};

    int kv0 = wid * 256;

    bf16x8 kr[2][8];
    #pragma unroll
    for (int kt = 0; kt < 4; ++kt) {
        const short* Kp = Kb + (kv0 + kt * 16 + l15) * 64 + lg * 8;
        kr[0][kt * 2]     = *(const bf16x8*)Kp;
        kr[0][kt * 2 + 1] = *(const bf16x8*)(Kp + 32);
    }

    #pragma unroll
    for (int t = 0; t < 4; ++t) {
        int kv = kv0 + t * 64;

        bf16x8 vr[8];
        #pragma unroll
        for (int ps = 0; ps < 2; ++ps)
            #pragma unroll
            for (int tt = 0; tt < 4; ++tt)
                vr[ps * 4 + tt] = *(const bf16x8*)(Vb + (tt * 16 + l15) * 2048 + kv + ps * 32 + lg * 8);

        f32x4 s[2][4];
        __builtin_amdgcn_s_setprio(1);
        #pragma unroll
        for (int kt = 0; kt < 4; ++kt) {
            f32x4 z0 = (f32x4){0.f, 0.f, 0.f, 0.f};
            z0 = __builtin_amdgcn_mfma_f32_16x16x32_bf16(kr[t & 1][kt * 2], bq[0][0], z0, 0, 0, 0);
            s[0][kt] = __builtin_amdgcn_mfma_f32_16x16x32_bf16(kr[t & 1][kt * 2 + 1], bq[0][1], z0, 0, 0, 0);
            f32x4 z1 = (f32x4){0.f, 0.f, 0.f, 0.f};
            z1 = __builtin_amdgcn_mfma_f32_16x16x32_bf16(kr[t & 1][kt * 2], bq[1][0], z1, 0, 0, 0);
            s[1][kt] = __builtin_amdgcn_mfma_f32_16x16x32_bf16(kr[t & 1][kt * 2 + 1], bq[1][1], z1, 0, 0, 0);
        }
        __builtin_amdgcn_s_setprio(0);

        if (t < 3) {
            #pragma unroll
            for (int kt = 0; kt < 4; ++kt) {
                const short* Kp = Kb + (kv + 64 + kt * 16 + l15) * 64 + lg * 8;
                kr[(t + 1) & 1][kt * 2]     = *(const bf16x8*)Kp;
                kr[(t + 1) & 1][kt * 2 + 1] = *(const bf16x8*)(Kp + 32);
            }
        }

        #pragma unroll
        for (int qg = 0; qg < 2; ++qg) {
            float m01 = fmaxf(fmaxf(s[qg][0][0], s[qg][0][1]), fmaxf(s[qg][0][2], s[qg][0][3]));
            float m23 = fmaxf(fmaxf(s[qg][1][0], s[qg][1][1]), fmaxf(s[qg][1][2], s[qg][1][3]));
            float m45 = fmaxf(fmaxf(s[qg][2][0], s[qg][2][1]), fmaxf(s[qg][2][2], s[qg][2][3]));
            float m67 = fmaxf(fmaxf(s[qg][3][0], s[qg][3][1]), fmaxf(s[qg][3][2], s[qg][3][3]));
            float mt = fmaxf(fmaxf(m01, m23), fmaxf(m45, m67));
            mt = fmaxf(mt, __shfl_xor(mt, 16));
            mt = fmaxf(mt, __shfl_xor(mt, 32));
            if (!__all(mt - m_run[qg] <= 8.0f)) {
                float mn = fmaxf(m_run[qg], mt);
                float c = exp2f(m_run[qg] - mn);
                m_run[qg] = mn;
                l_run[qg] *= c;
                #pragma unroll
                for (int tt = 0; tt < 4; ++tt)
                    #pragma unroll
                    for (int r = 0; r < 4; ++r) acc[qg][tt][r] *= c;
            }
            float rs = 0.f;
            #pragma unroll
            for (int kt = 0; kt < 4; ++kt)
                #pragma unroll
                for (int r = 0; r < 4; ++r) {
                    float p = exp2f(s[qg][kt][r] - m_run[qg]);
                    s[qg][kt][r] = p;
                    rs += p;
                }
            rs += __shfl_xor(rs, 16);
            rs += __shfl_xor(rs, 32);
            l_run[qg] += rs;
        }

        #pragma unroll
        for (int qg = 0; qg < 2; ++qg)
            #pragma unroll
            for (int kt = 0; kt < 4; ++kt) {
                union { u16x4 v; unsigned u[2]; } h;
                h.u[0] = pk2(s[qg][kt][0], s[qg][kt][1]);
                h.u[1] = pk2(s[qg][kt][2], s[qg][kt][3]);
                *(u16x4*)&P[(qg * 16 + l15) * 72 + kt * 16 + lg * 4] = h.v;
            }

        __builtin_amdgcn_s_setprio(1);
        #pragma unroll
        for (int ps = 0; ps < 2; ++ps) {
            bf16x8 bp0 = *(const bf16x8*)&P[l15 * 72 + ps * 32 + lg * 8];
            bf16x8 bp1 = *(const bf16x8*)&P[(16 + l15) * 72 + ps * 32 + lg * 8];
            #pragma unroll
            for (int tt = 0; tt < 4; ++tt) {
                acc[0][tt] = __builtin_amdgcn_mfma_f32_16x16x32_bf16(vr[ps * 4 + tt], bp0, acc[0][tt], 0, 0, 0);
                acc[1][tt] = __builtin_amdgcn_mfma_f32_16x16x32_bf16(vr[ps * 4 + tt], bp1, acc[1][tt], 0, 0, 0);
            }
        }
        __builtin_amdgcn_s_setprio(0);
    }

    if (lg == 0) {
        #pragma unroll
        for (int qg = 0; qg < 2; ++qg) {
            Mw[wid][qg * 16 + l15] = m_run[qg];
            Lw[wid][qg * 16 + l15] = l_run[qg];
        }
    }
    __syncthreads();   // all PV reads of P done; ubuf reusable as accw

    float* accw = (float*)&ubuf[wid][0];       // [32][68]
    #pragma unroll
    for (int qg = 0; qg < 2; ++qg) {
        int row = qg * 16 + l15;
        float m = Mw[0][row];
        #pragma unroll
        for (int w = 1; w < 8; ++w) m = fmaxf(m, Mw[w][row]);
        float fac = exp2f(m_run[qg] - m);
        #pragma unroll
        for (int t = 0; t < 4; ++t) {
            f32x4 v = acc[qg][t];
            v[0] *= fac; v[1] *= fac; v[2] *= fac; v[3] *= fac;
            *(f32x4*)&accw[row * 68 + t * 16 + lg * 4] = v;
        }
    }

    if (wid == 0 && lg == 0) {
        #pragma unroll
        for (int qg = 0; qg < 2; ++qg) {
            int row = qg * 16 + l15;
            float m = Mw[0][row];
            #pragma unroll
            for (int w = 1; w < 8; ++w) m = fmaxf(m, Mw[w][row]);
            float L = 0.f;
            #pragma unroll
            for (int w = 0; w < 8; ++w)
                L += Lw[w][row] * exp2f(Mw[w][row] - m);
            Ltot[row] = L;
        }
    }
    __syncthreads();

    #pragma unroll
    for (int j = 0; j < 4; ++j) {
        int o = tid + j * 512;
        int row = o >> 6, col = o & 63;
        float ssum = 0.f;
        #pragma unroll
        for (int w = 0; w < 8; ++w)
            ssum += ((const float*)&ubuf[w][0])[row * 68 + col];
        out[(b_ * 2048 + q0 + row) * 64 + col] = ssum / Ltot[row];
    }
}

extern "C" void kernel_launch(void* const* d_in, const int* in_sizes, int n_in,
                              void* d_out, int out_size, void* d_ws, size_t ws_size,
                              hipStream_t stream) {
    const float* x  = (const float*)d_in[0];
    const float* Wq = (const float*)d_in[1];
    const float* Wk = (const float*)d_in[2];
    const float* Wv = (const float*)d_in[3];
    float* out = (float*)d_out;

    char* ws = (char*)d_ws;
    short* Wt = (short*)ws;                              // 393216 B
    short* Q  = (short*)(ws + 393216);                   // 1048576 B
    short* K  = (short*)(ws + 393216 + 1048576);         // 1048576 B
    short* Vt = (short*)(ws + 393216 + 2 * 1048576);     // 1048576 B  (~3.4 MB total)

    hipLaunchKernelGGL(wtrans,   dim3(48),  dim3(256), 0, stream, Wq, Wk, Wv, Wt);
    hipLaunchKernelGGL(qkv_proj, dim3(512), dim3(256), 0, stream, x, Wt, Q, K, Vt);
    hipLaunchKernelGGL(attn32,   dim3(256), dim3(512), 0, stream, Q, K, Vt, out);
}